// Round 11
// baseline (2084.861 us; speedup 1.0000x reference)
//
#include <hip/hip_runtime.h>
#include <cmath>

namespace {
constexpr int B_ = 16, T_ = 512, P_ = 256, E_ = 128, NB_ = 4, K_ = 4;

__device__ __forceinline__ float rcpf(float x) { return __builtin_amdgcn_rcpf(x); }
__device__ __forceinline__ float fast_tanh(float x) {
    float a = fabsf(x);
    float t = __expf(-2.0f * a);
    float r = 1.0f - 2.0f * t * rcpf(1.0f + t);
    return copysignf(r, x);
}
// sum over the 4 kq groups (lanes l, l^16, l^32, l^48)
__device__ __forceinline__ float redkq(float v) {
    v += __shfl_xor(v, 16);
    v += __shfl_xor(v, 32);
    return v;
}
__device__ __forceinline__ float sel4(int kq, float a, float b, float c, float d) {
    const float t0 = (kq & 1) ? b : a;
    const float t1 = (kq & 1) ? d : c;
    return (kq & 2) ? t1 : t0;
}
}

// 512 threads / 8 waves, 1 block per batch (2 waves/SIMD -> latency hiding).
// Group g = waves 4g..4g+3 owns bots 2g, 2g+1 and covers ALL 128 e with the
// R9/R10 per-lane mapping (wl = w&3, e0 = ((wl<<4)|sub)<<1, kq = l>>4).
// Level scheduling as R10; cross-group corrections via svp planes (published
// in phase B, read after the inter-level barrier; coef=0 pairs make benign
// races: finite*0). Per-bot arithmetic order identical to R10 -> trajectories
// bit-identical.
__global__ __launch_bounds__(512, 1)
void swarm_ring_kernel(const float* __restrict__ x,            // (B,T,8)
                       const float* __restrict__ W_in,         // (8,E)
                       const float* __restrict__ b_in,         // (E)
                       const float* __restrict__ W_out,        // (E,8)
                       const float* __restrict__ b_out,        // (8)
                       const float* __restrict__ W_p,          // (E,E)
                       const float* __restrict__ b_p,          // (E)
                       const float* __restrict__ ptr_dest,     // (NB,P)
                       const float* __restrict__ jump_W,       // (NB,E)
                       const float* __restrict__ jump_b,       // (NB)
                       const float* __restrict__ ctx_strength, // (NB)
                       const float* __restrict__ phase_bias,   // (NB,E)
                       const float* __restrict__ pointer_init, // (NB,B)
                       float* __restrict__ out)                // (B,T,8)
{
    __shared__ alignas(16) float ring[P_ * E_];     // 128 KiB
    __shared__ alignas(16) float s1p[NB_ * E_];     // per-bot s1 planes
    __shared__ alignas(16) float svp[NB_ * E_];     // per-bot s2 planes (published)
    __shared__ alignas(16) float red[16];           // jump partials [2w+lb]
    __shared__ alignas(16) float hist2[2][16][132]; // per-group ssum history
    __shared__ alignas(16) float wout_s[8][132];    // 0.25 * W_out^T

    const int tid = threadIdx.x;
    const int b   = blockIdx.x;
    const int w   = tid >> 6;                       // 0..7
    const int l   = tid & 63;
    const int grp = w >> 2;                         // 0: bots 0,1 ; 1: bots 2,3
    const int wl  = w & 3;
    const int sub = l & 15;
    const int kq  = l >> 4;                         // 0..3
    const int e0  = ((wl << 4) | sub) << 1;         // owned e-pair

    for (int k4 = tid; k4 < P_ * E_ / 4; k4 += 512)
        ((float4*)ring)[k4] = make_float4(0.f, 0.f, 0.f, 0.f);
    for (int idx = tid; idx < 8 * E_; idx += 512) {
        const int m = idx >> 7, ee = idx & 127;
        wout_s[m][ee] = W_out[ee * 8 + m] * 0.25f;
    }

    float2 wp2[32];                                 // W_p[32*kq+kk][e0..e0+1]
    #pragma unroll
    for (int kk = 0; kk < 32; ++kk)
        wp2[kk] = *(const float2*)(W_p + (kq * 32 + kk) * E_ + e0);

    const float2 bin2 = *(const float2*)(b_in + e0);
    const float2 bp2  = *(const float2*)(b_p + e0);
    const float  bout_m = b_out[tid & 7];

    // global-bot uniform state (all lanes)
    float jb_r[NB_], ptrv[NB_];
    #pragma unroll
    for (int i = 0; i < NB_; ++i) {
        jb_r[i] = jump_b[i];
        ptrv[i] = pointer_init[i * B_ + b];
    }
    // owned-bot per-e state
    float2 pb2L[2], jw2L[2], hid2L[2];
    float  sigcL[2];
    #pragma unroll
    for (int lb = 0; lb < 2; ++lb) {
        const int j = (grp << 1) + lb;
        const float2 pb = *(const float2*)(phase_bias + j * E_ + e0);
        pb2L[lb] = make_float2(0.1f * pb.x, 0.1f * pb.y);
        jw2L[lb] = *(const float2*)(jump_W + j * E_ + e0);
        sigcL[lb] = 1.0f / (1.0f + __expf(-ctx_strength[j]));
        hid2L[lb] = make_float2(0.f, 0.f);
    }

    const float* xb = x + (size_t)b * T_ * 8;
    float xt[8];
    {
        float4 a0 = ((const float4*)xb)[0], a1 = ((const float4*)xb)[1];
        xt[0]=a0.x; xt[1]=a0.y; xt[2]=a0.z; xt[3]=a0.w;
        xt[4]=a1.x; xt[5]=a1.y; xt[6]=a1.z; xt[7]=a1.w;
    }

    const float Cw1 = 0.8824969f, Cw2 = 0.60653066f, Cw3 = 0.32465247f, Cw4 = 0.13533528f;
    const float Dw1 = 0.7788008f, Dw2 = 0.36787944f, Dw3 = 0.105399225f, Dw4 = 0.018315639f;

    __syncthreads();

    for (int t = 0; t < T_; ++t) {
        // ---- all-bot geometry (uniform); owned rows -> wgtL
        int   base[NB_];
        float fA[NB_], psinv[NB_], jt4[NB_];
        float wgtL[2][9];
        #pragma unroll
        for (int lb = 0; lb < 2; ++lb)
            #pragma unroll
            for (int o = 0; o < 9; ++o) wgtL[lb][o] = 0.f;
        #pragma unroll
        for (int i = 0; i < NB_; ++i) {
            const float p = ptrv[i];
            const int bs = (int)p;
            base[i] = bs;
            jt4[i] = ptr_dest[i * P_ + bs];
            const float f = p - (float)bs;
            fA[i] = f;
            const float r  = __expf(0.25f * f);
            const float r2 = r * r, r3 = r2 * r, r4 = r2 * r2;
            const float ri = rcpf(r), ri2 = ri * ri, ri3 = ri2 * ri, ri4 = ri2 * ri2;
            const float p0 = Cw4*ri4, p1 = Cw3*ri3, p2 = Cw2*ri2, p3 = Cw1*ri, p4 = 1.0f,
                        p5 = Cw1*r,  p6 = Cw2*r2,  p7 = Cw3*r3,  p8 = Cw4*r4;
            const float sum = ((p0+p1)+(p2+p3)) + ((p4+p5)+(p6+p7)) + p8;
            const float inv = rcpf(sum);
            psinv[i] = inv;
            if ((i >> 1) == grp) {                   // wave-uniform
                const int lb = i & 1;                // compile-time
                wgtL[lb][0]=p0*inv; wgtL[lb][1]=p1*inv; wgtL[lb][2]=p2*inv;
                wgtL[lb][3]=p3*inv; wgtL[lb][4]=p4*inv; wgtL[lb][5]=p5*inv;
                wgtL[lb][6]=p6*inv; wgtL[lb][7]=p7*inv; wgtL[lb][8]=p8*inv;
            }
        }

        // ---- overlap DAG -> levels (uniform, as R10)
        int lev[NB_];
        lev[0] = 0;
        #pragma unroll
        for (int j = 1; j < NB_; ++j) {
            int mx = -1;
            #pragma unroll
            for (int i = 0; i < j; ++i) {
                const int dd = ((base[j] - base[i] + 128) & 255) - 128;
                if (dd >= -8 && dd <= 8 && lev[i] > mx) mx = lev[i];
            }
            lev[j] = mx + 1;
        }
        const int m01 = lev[1] > lev[0] ? lev[1] : lev[0];
        const int m23 = lev[2] > lev[3] ? lev[2] : lev[3];
        const int nlev = 1 + (m01 > m23 ? m01 : m23);
        const int levL[2] = {grp ? lev[2] : lev[0], grp ? lev[3] : lev[1]};
        const int baseL[2] = {grp ? base[2] : base[0], grp ? base[3] : base[1]};
        const float fL[2] = {grp ? fA[2] : fA[0], grp ? fA[3] : fA[1]};
        const float psL[2] = {grp ? psinv[2] : psinv[0], grp ? psinv[3] : psinv[1]};

        // ---- correction coefs for owned rows: cm[lb][i], i = global 0..2
        float cm[2][3];
        bool  needcL[2] = {false, false};
        #pragma unroll
        for (int lb = 0; lb < 2; ++lb) {
            #pragma unroll
            for (int i = 0; i < 3; ++i) {
                cm[lb][i] = 0.f;
                const bool valid = grp ? (i < 2 + lb) : (lb == 1 && i == 0);
                if (valid) {                          // wave-uniform
                    const int dd = ((baseL[lb] - base[i] + 128) & 255) - 128;
                    if (dd >= -8 && dd <= 8) {
                        const float A = (float)dd - fA[i];
                        const float s  = __expf(-0.25f * (A - fL[lb]));
                        const float G  = __expf(0.125f * (fA[i] * fA[i] - A * A));
                        const float s2p = s * s, s3p = s2p * s, s4p = s2p * s2p;
                        const float si = rcpf(s), si2 = si * si, si3 = si2 * si, si4 = si2 * si2;
                        float acc = 0.f;
                        acc += (dd >= 0)              ? Dw4 * si4 : 0.f;
                        acc += (dd >= -1 && dd <= 7)  ? Dw3 * si3 : 0.f;
                        acc += (dd >= -2 && dd <= 6)  ? Dw2 * si2 : 0.f;
                        acc += (dd >= -3 && dd <= 5)  ? Dw1 * si  : 0.f;
                        acc += (dd >= -4 && dd <= 4)  ? 1.0f      : 0.f;
                        acc += (dd >= -5 && dd <= 3)  ? Dw1 * s   : 0.f;
                        acc += (dd >= -6 && dd <= 2)  ? Dw2 * s2p : 0.f;
                        acc += (dd >= -7 && dd <= 1)  ? Dw3 * s3p : 0.f;
                        acc += (dd <= 0)              ? Dw4 * s4p : 0.f;
                        cm[lb][i] = psinv[i] * psL[lb] * G * acc;
                        needcL[lb] = true;
                    }
                }
            }
        }

        // ---- gathers for owned bots (R9 pattern)
        float  ws0L[2], ws1L[2];
        float2 ctxpL[2];
        #pragma unroll
        for (int lb = 0; lb < 2; ++lb) {
            ws0L[lb] = sel4(kq, wgtL[lb][0], wgtL[lb][1], wgtL[lb][2], wgtL[lb][3]);
            ws1L[lb] = sel4(kq, wgtL[lb][4], wgtL[lb][5], wgtL[lb][6], wgtL[lb][7]);
            const int r0 = (baseL[lb] + kq - K_) & (P_ - 1);
            const int r1 = (baseL[lb] + kq + 4 - K_) & (P_ - 1);
            const float2 g0 = *(const float2*)(ring + r0 * E_ + e0);
            const float2 g1 = *(const float2*)(ring + r1 * E_ + e0);
            float cx = fmaf(ws1L[lb], g1.x, ws0L[lb] * g0.x);
            float cy = fmaf(ws1L[lb], g1.y, ws0L[lb] * g0.y);
            if (kq == 0) {
                const int r2 = (baseL[lb] + 8 - K_) & (P_ - 1);
                const float2 g2 = *(const float2*)(ring + r2 * E_ + e0);
                cx = fmaf(wgtL[lb][8], g2.x, cx);
                cy = fmaf(wgtL[lb][8], g2.y, cy);
            }
            ctxpL[lb] = make_float2(redkq(cx), redkq(cy));
        }

        // ---- inp = x_t @ W_in + b_in
        float2 inp2 = bin2;
        #pragma unroll
        for (int k = 0; k < 8; ++k) {
            const float2 wk = *(const float2*)(W_in + k * E_ + e0);
            inp2.x = fmaf(xt[k], wk.x, inp2.x);
            inp2.y = fmaf(xt[k], wk.y, inp2.y);
        }

        float xtn[8];
        if (t + 1 < T_) {
            float4 a0 = ((const float4*)(xb + (t + 1) * 8))[0];
            float4 a1 = ((const float4*)(xb + (t + 1) * 8))[1];
            xtn[0]=a0.x; xtn[1]=a0.y; xtn[2]=a0.z; xtn[3]=a0.w;
            xtn[4]=a1.x; xtn[5]=a1.y; xtn[6]=a1.z; xtn[7]=a1.w;
        } else {
            #pragma unroll
            for (int k = 0; k < 8; ++k) xtn[k] = 0.f;
        }

        // ---- level-scheduled execution (group handles its own bots)
        float2 sv2L[2] = {make_float2(0.f, 0.f), make_float2(0.f, 0.f)};

        for (int L = 0; L < nlev; ++L) {
            // phase A: s1 for owned level-L bots
            #pragma unroll
            for (int lb = 0; lb < 2; ++lb) {
                if (levL[lb] != L) continue;         // wave-uniform
                const int jg = (grp << 1) + lb;
                float2 ctx = ctxpL[lb];
                if (needcL[lb]) {                    // wave-uniform
                    #pragma unroll
                    for (int i = 0; i < 3; ++i) {
                        const bool valid = grp ? (i < 2 + lb) : (lb == 1 && i == 0);
                        if (valid) {
                            const bool sameGrp = (i >> 1) == grp;
                            float2 si;
                            if (sameGrp) si = sv2L[0];   // partner (earlier local bot)
                            else         si = *(const float2*)(svp + i * E_ + e0);
                            ctx.x = fmaf(cm[lb][i], si.x, ctx.x);
                            ctx.y = fmaf(cm[lb][i], si.y, ctx.y);
                        }
                    }
                }
                float2 s1;
                s1.x = fast_tanh(fmaf(sigcL[lb], ctx.x, inp2.x + pb2L[lb].x + hid2L[lb].x));
                s1.y = fast_tanh(fmaf(sigcL[lb], ctx.y, inp2.y + pb2L[lb].y + hid2L[lb].y));
                if (kq == 0) *(float2*)(s1p + jg * E_ + e0) = s1;
            }
            __syncthreads();                         // s1 planes (+ svp of prev level)

            // phase B: matvec + s2 + publish + scatter
            #pragma unroll
            for (int lb = 0; lb < 2; ++lb) {
                if (levL[lb] != L) continue;         // wave-uniform
                const int jg = (grp << 1) + lb;
                const float4* sp = (const float4*)(s1p + jg * E_) + kq * 8;
                float ax = 0.f, ay = 0.f;
                #pragma unroll
                for (int kk = 0; kk < 8; ++kk) {
                    const float4 sq = sp[kk];
                    const float2 wa = wp2[4 * kk + 0], wb = wp2[4 * kk + 1];
                    const float2 wc = wp2[4 * kk + 2], wd = wp2[4 * kk + 3];
                    ax = fmaf(sq.x, wa.x, ax); ay = fmaf(sq.x, wa.y, ay);
                    ax = fmaf(sq.y, wb.x, ax); ay = fmaf(sq.y, wb.y, ay);
                    ax = fmaf(sq.z, wc.x, ax); ay = fmaf(sq.z, wc.y, ay);
                    ax = fmaf(sq.w, wd.x, ax); ay = fmaf(sq.w, wd.y, ay);
                }
                float2 s2;
                s2.x = fast_tanh(redkq(ax) + bp2.x);
                s2.y = fast_tanh(redkq(ay) + bp2.y);
                sv2L[lb] = s2; hid2L[lb] = s2;
                if (kq == 0) *(float2*)(svp + jg * E_ + e0) = s2;

                const int r0 = (baseL[lb] + kq - K_) & (P_ - 1);
                float2* q0 = (float2*)(ring + r0 * E_ + e0);
                float2 v0 = *q0;
                v0.x = fmaf(ws0L[lb], s2.x, v0.x); v0.y = fmaf(ws0L[lb], s2.y, v0.y);
                *q0 = v0;
                const int r1 = (baseL[lb] + kq + 4 - K_) & (P_ - 1);
                float2* q1 = (float2*)(ring + r1 * E_ + e0);
                float2 v1 = *q1;
                v1.x = fmaf(ws1L[lb], s2.x, v1.x); v1.y = fmaf(ws1L[lb], s2.y, v1.y);
                *q1 = v1;
                if (kq == 0) {
                    const int r2 = (baseL[lb] + 8 - K_) & (P_ - 1);
                    float2* q2 = (float2*)(ring + r2 * E_ + e0);
                    float2 v2 = *q2;
                    v2.x = fmaf(wgtL[lb][8], s2.x, v2.x); v2.y = fmaf(wgtL[lb][8], s2.y, v2.y);
                    *q2 = v2;
                }
            }
            if (L + 1 < nlev) __syncthreads();       // svp/scatter ordering across levels
        }

        // ---- jump dots for owned bots (reduce over this wave's 16 subs)
        {
            float vjA = fmaf(sv2L[0].y, jw2L[0].y, sv2L[0].x * jw2L[0].x);
            float vjB = fmaf(sv2L[1].y, jw2L[1].y, sv2L[1].x * jw2L[1].x);
            #pragma unroll
            for (int off = 1; off < 16; off <<= 1) {
                vjA += __shfl_xor(vjA, off);
                vjB += __shfl_xor(vjB, off);
            }
            if (l == 0) ((float2*)red)[w] = make_float2(vjA, vjB);
        }

        // ---- group-partial ssum -> history plane
        {
            float2 ss2;
            ss2.x = sv2L[0].x + sv2L[1].x;
            ss2.y = sv2L[0].y + sv2L[1].y;
            if (kq == 0) *(float2*)(&hist2[grp][t & 15][e0]) = ss2;
        }

        __syncthreads();                             // scatters + red + hist visible

        // ---- pointer updates (all lanes; compile-time red indices)
        {
            float zz[NB_];
            #pragma unroll
            for (int i = 0; i < NB_; ++i) {
                const int g = i >> 1, o = i & 1;
                zz[i] = ((red[2 * (4 * g + 0) + o] + red[2 * (4 * g + 1) + o]) +
                         (red[2 * (4 * g + 2) + o] + red[2 * (4 * g + 3) + o])) + jb_r[i];
            }
            #pragma unroll
            for (int i = 0; i < NB_; ++i) {
                float np;
                if (zz[i] > 0.0f) np = jt4[i];
                else { np = ptrv[i] + 1.0f; if (np >= 256.0f) np -= 256.0f; }
                ptrv[i] = np;
            }
        }

        // ---- every 8th step: deferred out dots (adds the two group planes)
        if ((t & 7) == 7 && tid < 64) {
            const int tt = tid >> 3;
            const int m  = tid & 7;
            const int row = (t - 7 + tt) & 15;
            const float* hA = hist2[0][row];
            const float* hB = hist2[1][row];
            const float* wrow = wout_s[m];
            float acc = 0.f;
            #pragma unroll
            for (int q = 0; q < 32; ++q) {
                const float4 a4 = ((const float4*)hA)[q];
                const float4 b4 = ((const float4*)hB)[q];
                const float4 w4 = ((const float4*)wrow)[q];
                acc += (((a4.x + b4.x) * w4.x + (a4.y + b4.y) * w4.y) +
                        ((a4.z + b4.z) * w4.z + (a4.w + b4.w) * w4.w));
            }
            out[((size_t)b * T_ + (t - 7 + tt)) * 8 + m] = acc + bout_m;
        }

        #pragma unroll
        for (int k = 0; k < 8; ++k) xt[k] = xtn[k];
    }
}

extern "C" void kernel_launch(void* const* d_in, const int* in_sizes, int n_in,
                              void* d_out, int out_size, void* d_ws, size_t ws_size,
                              hipStream_t stream) {
    (void)in_sizes; (void)n_in; (void)out_size; (void)d_ws; (void)ws_size;
    swarm_ring_kernel<<<dim3(B_), dim3(512), 0, stream>>>(
        (const float*)d_in[0],  (const float*)d_in[1],  (const float*)d_in[2],
        (const float*)d_in[3],  (const float*)d_in[4],  (const float*)d_in[5],
        (const float*)d_in[6],  (const float*)d_in[7],  (const float*)d_in[8],
        (const float*)d_in[9],  (const float*)d_in[10], (const float*)d_in[11],
        (const float*)d_in[12], (float*)d_out);
}